// Round 3
// baseline (1093.986 us; speedup 1.0000x reference)
//
#include <hip/hip_runtime.h>
#include <stdint.h>

#define B_TOK 8192
#define DDIM 1024
#define HDIM 4096
#define NEXP 8

typedef __bf16 bf16x8 __attribute__((ext_vector_type(8)));
typedef float f32x4 __attribute__((ext_vector_type(4)));

__device__ __forceinline__ unsigned short f2bf(float f) {
  unsigned int u = __float_as_uint(f);
  u += 0x7fffu + ((u >> 16) & 1u);  // round-to-nearest-even
  return (unsigned short)(u >> 16);
}
__device__ __forceinline__ float bfhi(unsigned int u) { return __uint_as_float(u & 0xffff0000u); }
__device__ __forceinline__ float bflo(unsigned int u) { return __uint_as_float(u << 16); }

__device__ __forceinline__ void gld16(const void* g, void* l) {
  __builtin_amdgcn_global_load_lds(
      (const __attribute__((address_space(1))) void*)g,
      (__attribute__((address_space(3))) void*)l, 16, 0, 0);
}

// tanh-form GELU; max abs err ~3e-4 (well under bf16 rounding of h)
__device__ __forceinline__ float gelu_f(float v) {
  float u = v * (0.7978845608f + 0.0356774081f * v * v);
  float ex = __expf(2.f * u);
  float th = 1.f - 2.f * __builtin_amdgcn_rcpf(ex + 1.f);
  return 0.5f * v * (1.f + th);
}

// ---------------- gating ----------------
__global__ __launch_bounds__(256) void gating_kernel(
    const float* __restrict__ x, const float* __restrict__ Wg,
    const float* __restrict__ bg, int* __restrict__ t2e,
    float* __restrict__ t2w, int* __restrict__ cnt) {
  __shared__ float sWg[NEXP * DDIM];  // [e][d]
  int tid = threadIdx.x;
  for (int i = tid; i < NEXP * DDIM; i += 256) {
    int d = i >> 3, e = i & 7;
    sWg[e * DDIM + d] = Wg[i];
  }
  __syncthreads();
  int lane = tid & 63, wave = tid >> 6;
  for (int t = 0; t < 16; ++t) {
    int b = blockIdx.x * 64 + wave * 16 + t;
    float acc[NEXP];
#pragma unroll
    for (int e = 0; e < NEXP; ++e) acc[e] = 0.f;
    const float* xr = x + (size_t)b * DDIM;
#pragma unroll
    for (int j = 0; j < 4; ++j) {
      int d0 = j * 256 + lane * 4;
      float4 xv = *(const float4*)(xr + d0);
#pragma unroll
      for (int e = 0; e < NEXP; ++e) {
        float4 wv = *(const float4*)(sWg + e * DDIM + d0);
        acc[e] += xv.x * wv.x + xv.y * wv.y + xv.z * wv.z + xv.w * wv.w;
      }
    }
#pragma unroll
    for (int off = 32; off > 0; off >>= 1) {
#pragma unroll
      for (int e = 0; e < NEXP; ++e) acc[e] += __shfl_xor(acc[e], off);
    }
    if (lane == 0) {
      float l0[NEXP];
#pragma unroll
      for (int e = 0; e < NEXP; ++e) l0[e] = acc[e] + bg[e];
      int i1 = 0;
      float v1 = l0[0];
#pragma unroll
      for (int e = 1; e < NEXP; ++e)
        if (l0[e] > v1) { v1 = l0[e]; i1 = e; }
      int i2 = (i1 == 0) ? 1 : 0;
      float v2 = l0[i2];
#pragma unroll
      for (int e = 0; e < NEXP; ++e)
        if (e != i1 && l0[e] > v2) { v2 = l0[e]; i2 = e; }
      float w1 = 1.f / (1.f + expf(v2 - v1));
      float w2 = 1.f - w1;
      t2e[b * 2] = i1;
      t2e[b * 2 + 1] = i2;
      t2w[b * 2] = w1;
      t2w[b * 2 + 1] = w2;
      atomicAdd(&cnt[i1], 1);
      atomicAdd(&cnt[i2], 1);
    }
  }
}

__global__ void prefix_kernel(const int* __restrict__ cnt, int* __restrict__ offs,
                              int* __restrict__ tileE, int* __restrict__ tileM,
                              int* __restrict__ ntile) {
  int s = 0, t = 0;
  offs[0] = 0;
  for (int e = 0; e < NEXP; ++e) {
    int c = cnt[e];
    for (int m = 0; m < c; m += 128) { tileE[t] = e; tileM[t] = m; ++t; }
    s += c;
    offs[e + 1] = s;
  }
  *ntile = t;
}

__global__ __launch_bounds__(256) void scatter_kernel(
    const int* __restrict__ t2e, const int* __restrict__ offs,
    int* __restrict__ cursor, int* __restrict__ tok, int* __restrict__ rowpos) {
  int b = blockIdx.x * 256 + threadIdx.x;
  if (b >= B_TOK) return;
#pragma unroll
  for (int k = 0; k < 2; ++k) {
    int e = t2e[b * 2 + k];
    int pos = offs[e] + atomicAdd(&cursor[e], 1);
    tok[pos] = b;
    rowpos[b * 2 + k] = pos;
  }
}

// ---------------- prep ----------------
__global__ __launch_bounds__(256) void cvt_x_kernel(const float* __restrict__ x,
                                                    unsigned short* __restrict__ xb) {
  size_t i = ((size_t)blockIdx.x * 256 + threadIdx.x) * 4;
  float4 v = *(const float4*)(x + i);
  ushort4 o;
  o.x = f2bf(v.x);
  o.y = f2bf(v.y);
  o.z = f2bf(v.z);
  o.w = f2bf(v.w);
  *(ushort4*)(xb + i) = o;
}

__global__ __launch_bounds__(256) void transpose_cvt_kernel(
    const float* __restrict__ src, unsigned short* __restrict__ dst, int R, int C) {
  __shared__ unsigned short T[64][72];
  size_t eo = (size_t)blockIdx.z * (size_t)R * C;
  int c0 = blockIdx.x * 64, r0 = blockIdx.y * 64;
  int tid = threadIdx.x;
#pragma unroll
  for (int p = 0; p < 4; ++p) {
    int idx = p * 256 + tid;
    int r = idx >> 4, c4 = (idx & 15) * 4;
    float4 v = *(const float4*)(src + eo + (size_t)(r0 + r) * C + c0 + c4);
    T[r][c4] = f2bf(v.x);
    T[r][c4 + 1] = f2bf(v.y);
    T[r][c4 + 2] = f2bf(v.z);
    T[r][c4 + 3] = f2bf(v.w);
  }
  __syncthreads();
#pragma unroll
  for (int p = 0; p < 2; ++p) {
    int idx = p * 256 + tid;
    int c = idx >> 3, s8 = (idx & 7) * 8;
    ushort4 a, b;
    a.x = T[s8][c];     a.y = T[s8 + 1][c]; a.z = T[s8 + 2][c]; a.w = T[s8 + 3][c];
    b.x = T[s8 + 4][c]; b.y = T[s8 + 5][c]; b.z = T[s8 + 6][c]; b.w = T[s8 + 7][c];
    unsigned short* dp = dst + eo + (size_t)(c0 + c) * R + r0 + s8;
    *(ushort4*)dp = a;
    *(ushort4*)(dp + 4) = b;
  }
}

// ================= GEMM cores: 128x128 tile, BK=64, XOR-swizzled LDS, =================
// ================= double-buffered, 1 barrier per K-iter (prefetch-first) ============
// LDS layout: row-major 128 rows x 128 B; within a row, 16-B chunk slot c holds
// global k-chunk (c ^ (row&7)). Fragment read (16 consecutive rows, fixed chunk)
// then spans all 8 bank-groups, 2 lanes each -> conflict-free [m136: 2-way is free].
// gld16 lane map: lane L -> row (L>>3), slot (L&7) -> loads global chunk (L&7)^(L>>3);
// the 8 lanes of a row still cover one contiguous 128-B segment (perfect coalescing).

// GEMM1: h = gelu(x_gathered @ W1[e]^T-layout + b1[e])
__global__ __launch_bounds__(256, 2) void gemm1_kernel(
    const unsigned short* __restrict__ xb, const unsigned short* __restrict__ w1t,
    const float* __restrict__ b1, const int* __restrict__ offs,
    const int* __restrict__ tileE, const int* __restrict__ tileM,
    const int* __restrict__ ntile, const int* __restrict__ tok,
    unsigned short* __restrict__ hbuf) {
  int ty = blockIdx.y;
  if (ty >= *ntile) return;
  int e = tileE[ty], m0 = tileM[ty];
  int r0 = offs[e], rows = offs[e + 1] - r0;
  int n0 = blockIdx.x * 128;

  __shared__ __attribute__((aligned(16))) unsigned short Xs[2 * 128 * 64];  // 32 KiB
  __shared__ __attribute__((aligned(16))) unsigned short Ws[2 * 128 * 64];  // 32 KiB

  int tid = threadIdx.x, lane = tid & 63, wave = tid >> 6;
  int r8 = lane >> 3, c8 = lane & 7;
  int swb = ((c8 ^ r8) * 16);  // byte offset of the global chunk this lane stages

  // staging pointers: wave u covers rows [u*32, u*32+32) of both tiles, 8 rows/gld16
  const char* pX[4];
  const char* pW[4];
#pragma unroll
  for (int g = 0; g < 4; ++g) {
    int rl = wave * 32 + g * 8 + r8;
    int gr = tok[r0 + min(m0 + rl, rows - 1)];
    pX[g] = (const char*)(xb + (size_t)gr * DDIM) + swb;
    pW[g] = (const char*)(w1t + ((size_t)e * HDIM + n0 + rl) * DDIM) + swb;
  }
  unsigned short* Xd = Xs + wave * 32 * 64;  // + buf*8192
  unsigned short* Wd = Ws + wave * 32 * 64;

  f32x4 acc[4][4];
#pragma unroll
  for (int i = 0; i < 4; ++i)
#pragma unroll
    for (int j = 0; j < 4; ++j) acc[i][j] = (f32x4){0.f, 0.f, 0.f, 0.f};

  int wn = wave & 1, wm = wave >> 1;
  int fr = lane & 15, quad = lane >> 4;
  int frb = fr * 64;                       // shorts
  int q0 = ((quad ^ (fr & 7)) * 8);        // k-step 0 chunk (shorts)
  int q1 = (((quad | 4) ^ (fr & 7)) * 8);  // k-step 1 chunk

#define STAGE1(buf, kb)                                   \
  {                                                       \
    _Pragma("unroll") for (int g = 0; g < 4; ++g) {       \
      gld16(pX[g] + (kb), Xd + (buf)*8192 + g * 512);     \
      gld16(pW[g] + (kb), Wd + (buf)*8192 + g * 512);     \
    }                                                     \
  }

  STAGE1(0, 0);
  __syncthreads();

  const int NIT = DDIM / 64;  // 16
  for (int kk = 0; kk < NIT; ++kk) {
    int cur = kk & 1;
    if (kk + 1 < NIT) STAGE1(cur ^ 1, (kk + 1) * 128);
    const unsigned short* Xb = Xs + cur * 8192 + wm * 64 * 64;
    const unsigned short* Wb = Ws + cur * 8192 + wn * 64 * 64;
#pragma unroll
    for (int s = 0; s < 2; ++s) {
      int qq = s ? q1 : q0;
      bf16x8 a[4], b[4];
#pragma unroll
      for (int i = 0; i < 4; ++i) {
        a[i] = *(const bf16x8*)(Wb + i * 16 * 64 + frb + qq);
        b[i] = *(const bf16x8*)(Xb + i * 16 * 64 + frb + qq);
      }
#pragma unroll
      for (int i = 0; i < 4; ++i)
#pragma unroll
        for (int j = 0; j < 4; ++j)
          acc[i][j] = __builtin_amdgcn_mfma_f32_16x16x32_bf16(a[i], b[j], acc[i][j], 0, 0, 0);
    }
    __syncthreads();
  }

  const float* b1e = b1 + (size_t)e * HDIM + n0 + wn * 64;
  float4 bias[4];
#pragma unroll
  for (int i = 0; i < 4; ++i) bias[i] = *(const float4*)(b1e + i * 16 + quad * 4);
#pragma unroll
  for (int j = 0; j < 4; ++j) {
    int grow = m0 + wm * 64 + j * 16 + fr;
    if (grow < rows) {
      unsigned short* hp = hbuf + (size_t)(r0 + grow) * HDIM + n0 + wn * 64;
#pragma unroll
      for (int i = 0; i < 4; ++i) {
        ushort4 o;
        o.x = f2bf(gelu_f(acc[i][j][0] + bias[i].x));
        o.y = f2bf(gelu_f(acc[i][j][1] + bias[i].y));
        o.z = f2bf(gelu_f(acc[i][j][2] + bias[i].z));
        o.w = f2bf(gelu_f(acc[i][j][3] + bias[i].w));
        *(ushort4*)(hp + i * 16 + quad * 4) = o;
      }
    }
  }
}

// GEMM2: ybuf[row] = h[row] @ W2[e] + b2[e]
__global__ __launch_bounds__(256, 2) void gemm2_kernel(
    const unsigned short* __restrict__ hbuf, const unsigned short* __restrict__ w2t,
    const float* __restrict__ b2, const int* __restrict__ offs,
    const int* __restrict__ tileE, const int* __restrict__ tileM,
    const int* __restrict__ ntile, unsigned short* __restrict__ ybuf) {
  int ty = blockIdx.y;
  if (ty >= *ntile) return;
  int e = tileE[ty], m0 = tileM[ty];
  int r0 = offs[e], rows = offs[e + 1] - r0;
  int n0 = blockIdx.x * 128;

  __shared__ __attribute__((aligned(16))) unsigned short Hs[2 * 128 * 64];
  __shared__ __attribute__((aligned(16))) unsigned short Ws[2 * 128 * 64];

  int tid = threadIdx.x, lane = tid & 63, wave = tid >> 6;
  int r8 = lane >> 3, c8 = lane & 7;
  int swb = ((c8 ^ r8) * 16);

  const char* pH[4];
  const char* pW[4];
#pragma unroll
  for (int g = 0; g < 4; ++g) {
    int rl = wave * 32 + g * 8 + r8;
    pH[g] = (const char*)(hbuf + (size_t)(r0 + min(m0 + rl, rows - 1)) * HDIM) + swb;
    pW[g] = (const char*)(w2t + ((size_t)e * DDIM + n0 + rl) * HDIM) + swb;
  }
  unsigned short* Hd = Hs + wave * 32 * 64;
  unsigned short* Wd = Ws + wave * 32 * 64;

  f32x4 acc[4][4];
#pragma unroll
  for (int i = 0; i < 4; ++i)
#pragma unroll
    for (int j = 0; j < 4; ++j) acc[i][j] = (f32x4){0.f, 0.f, 0.f, 0.f};

  int wn = wave & 1, wm = wave >> 1;
  int fr = lane & 15, quad = lane >> 4;
  int frb = fr * 64;
  int q0 = ((quad ^ (fr & 7)) * 8);
  int q1 = (((quad | 4) ^ (fr & 7)) * 8);

#define STAGE2(buf, kb)                                   \
  {                                                       \
    _Pragma("unroll") for (int g = 0; g < 4; ++g) {       \
      gld16(pH[g] + (kb), Hd + (buf)*8192 + g * 512);     \
      gld16(pW[g] + (kb), Wd + (buf)*8192 + g * 512);     \
    }                                                     \
  }

  STAGE2(0, 0);
  __syncthreads();

  const int NIT = HDIM / 64;  // 64
  for (int kk = 0; kk < NIT; ++kk) {
    int cur = kk & 1;
    if (kk + 1 < NIT) STAGE2(cur ^ 1, (kk + 1) * 128);
    const unsigned short* Hb = Hs + cur * 8192 + wm * 64 * 64;
    const unsigned short* Wb = Ws + cur * 8192 + wn * 64 * 64;
#pragma unroll
    for (int s = 0; s < 2; ++s) {
      int qq = s ? q1 : q0;
      bf16x8 a[4], b[4];
#pragma unroll
      for (int i = 0; i < 4; ++i) {
        a[i] = *(const bf16x8*)(Wb + i * 16 * 64 + frb + qq);
        b[i] = *(const bf16x8*)(Hb + i * 16 * 64 + frb + qq);
      }
#pragma unroll
      for (int i = 0; i < 4; ++i)
#pragma unroll
        for (int j = 0; j < 4; ++j)
          acc[i][j] = __builtin_amdgcn_mfma_f32_16x16x32_bf16(a[i], b[j], acc[i][j], 0, 0, 0);
    }
    __syncthreads();
  }

  const float* b2e = b2 + (size_t)e * DDIM + n0 + wn * 64;
  float4 bias[4];
#pragma unroll
  for (int i = 0; i < 4; ++i) bias[i] = *(const float4*)(b2e + i * 16 + quad * 4);
#pragma unroll
  for (int j = 0; j < 4; ++j) {
    int grow = m0 + wm * 64 + j * 16 + fr;
    if (grow < rows) {
      unsigned short* yp = ybuf + (size_t)(r0 + grow) * DDIM + n0 + wn * 64;
#pragma unroll
      for (int i = 0; i < 4; ++i) {
        ushort4 o;
        o.x = f2bf(acc[i][j][0] + bias[i].x);
        o.y = f2bf(acc[i][j][1] + bias[i].y);
        o.z = f2bf(acc[i][j][2] + bias[i].z);
        o.w = f2bf(acc[i][j][3] + bias[i].w);
        *(ushort4*)(yp + i * 16 + quad * 4) = o;
      }
    }
  }
}

// ---------------- combine ----------------
__global__ __launch_bounds__(256) void combine_kernel(
    const unsigned short* __restrict__ ybuf, const int* __restrict__ rowpos,
    const float* __restrict__ t2w, float* __restrict__ out) {
  int idx = blockIdx.x * 256 + threadIdx.x;
  int b = idx >> 7;
  int c8 = (idx & 127) * 8;
  int p0 = rowpos[b * 2], p1 = rowpos[b * 2 + 1];
  float w0 = t2w[b * 2], w1 = t2w[b * 2 + 1];
  uint4 ya = *(const uint4*)(ybuf + (size_t)p0 * DDIM + c8);
  uint4 yb = *(const uint4*)(ybuf + (size_t)p1 * DDIM + c8);
  float4 o0, o1;
  o0.x = w0 * bflo(ya.x) + w1 * bflo(yb.x);
  o0.y = w0 * bfhi(ya.x) + w1 * bfhi(yb.x);
  o0.z = w0 * bflo(ya.y) + w1 * bflo(yb.y);
  o0.w = w0 * bfhi(ya.y) + w1 * bfhi(yb.y);
  o1.x = w0 * bflo(ya.z) + w1 * bflo(yb.z);
  o1.y = w0 * bfhi(ya.z) + w1 * bfhi(yb.z);
  o1.z = w0 * bflo(ya.w) + w1 * bflo(yb.w);
  o1.w = w0 * bfhi(ya.w) + w1 * bfhi(yb.w);
  float* op = out + (size_t)b * DDIM + c8;
  *(float4*)op = o0;
  *(float4*)(op + 4) = o1;
}

extern "C" void kernel_launch(void* const* d_in, const int* in_sizes, int n_in,
                              void* d_out, int out_size, void* d_ws, size_t ws_size,
                              hipStream_t stream) {
  const float* x = (const float*)d_in[0];
  const float* Wg = (const float*)d_in[1];
  const float* bg = (const float*)d_in[2];
  const float* W1 = (const float*)d_in[3];
  const float* b1 = (const float*)d_in[4];
  const float* W2 = (const float*)d_in[5];
  const float* b2 = (const float*)d_in[6];
  float* out = (float*)d_out;

  char* ws = (char*)d_ws;
  int* cnt = (int*)(ws + 0);
  int* cursor = (int*)(ws + 64);
  int* offs = (int*)(ws + 128);
  int* ntile = (int*)(ws + 192);
  int* tileE = (int*)(ws + 256);
  int* tileM = (int*)(ws + 896);
  int* t2e = (int*)(ws + 2048);
  float* t2w = (float*)(ws + 67584);
  int* tok = (int*)(ws + 133120);
  int* rowpos = (int*)(ws + 198656);
  char* big = ws + 264192;
  unsigned short* xb = (unsigned short*)big;                               // 16 MiB
  unsigned short* w1t = (unsigned short*)(big + 16777216);                 // 64 MiB
  unsigned short* ybuf = w1t;  // alias: w1t dead after gemm1
  unsigned short* w2t = (unsigned short*)(big + 16777216 + 67108864);      // 64 MiB
  unsigned short* hbuf = (unsigned short*)(big + 16777216 + 2 * 67108864); // 128 MiB

  (void)in_sizes; (void)n_in; (void)out_size; (void)ws_size;

  hipMemsetAsync(ws, 0, 256, stream);

  cvt_x_kernel<<<(B_TOK * DDIM) / 1024, 256, 0, stream>>>(x, xb);
  transpose_cvt_kernel<<<dim3(HDIM / 64, DDIM / 64, NEXP), 256, 0, stream>>>(W1, w1t, DDIM, HDIM);
  transpose_cvt_kernel<<<dim3(DDIM / 64, HDIM / 64, NEXP), 256, 0, stream>>>(W2, w2t, HDIM, DDIM);
  gating_kernel<<<B_TOK / 64, 256, 0, stream>>>(x, Wg, bg, t2e, t2w, cnt);
  prefix_kernel<<<1, 1, 0, stream>>>(cnt, offs, tileE, tileM, ntile);
  scatter_kernel<<<B_TOK / 256, 256, 0, stream>>>(t2e, offs, cursor, tok, rowpos);
  gemm1_kernel<<<dim3(HDIM / 128, 136), 256, 0, stream>>>(xb, w1t, b1, offs, tileE, tileM, ntile, tok, hbuf);
  gemm2_kernel<<<dim3(DDIM / 128, 136), 256, 0, stream>>>(hbuf, w2t, b2, offs, tileE, tileM, ntile, ybuf);
  combine_kernel<<<(B_TOK * DDIM) / (256 * 8), 256, 0, stream>>>(ybuf, rowpos, t2w, out);
}